// Round 1
// baseline (819.832 us; speedup 1.0000x reference)
//
#include <hip/hip_runtime.h>

#define N_NODES 100000
#define N_EDGES 1600000
#define IN_DIM 128
#define DIM_H 64
#define N_GRAPHS 64

__device__ __forceinline__ float relu(float v) { return v > 0.f ? v : 0.f; }
#define BN_SCALE 0.99999500003749968f  /* 1/sqrt(1+1e-5) */

// ---------------- CSR build (counting sort by dst) ----------------
__global__ __launch_bounds__(256) void hist_kernel(const int* __restrict__ dst,
                                                   int* __restrict__ cnt) {
  int i = blockIdx.x * blockDim.x + threadIdx.x;
  for (; i < N_EDGES; i += gridDim.x * blockDim.x)
    atomicAdd(&cnt[dst[i]], 1);
}

__global__ __launch_bounds__(256) void scan1(const int* __restrict__ cnt,
                                             int* __restrict__ rp,
                                             int* __restrict__ bsum) {
  __shared__ int sd[256];
  int tid = threadIdx.x;
  int base = blockIdx.x * 1024 + tid * 4;
  int v0 = (base + 0 < N_NODES) ? cnt[base + 0] : 0;
  int v1 = (base + 1 < N_NODES) ? cnt[base + 1] : 0;
  int v2 = (base + 2 < N_NODES) ? cnt[base + 2] : 0;
  int v3 = (base + 3 < N_NODES) ? cnt[base + 3] : 0;
  int s = v0 + v1 + v2 + v3;
  sd[tid] = s;
  __syncthreads();
  for (int off = 1; off < 256; off <<= 1) {
    int t = (tid >= off) ? sd[tid - off] : 0;
    __syncthreads();
    sd[tid] += t;
    __syncthreads();
  }
  int excl = sd[tid] - s;
  if (base + 0 < N_NODES) rp[base + 0] = excl;
  if (base + 1 < N_NODES) rp[base + 1] = excl + v0;
  if (base + 2 < N_NODES) rp[base + 2] = excl + v0 + v1;
  if (base + 3 < N_NODES) rp[base + 3] = excl + v0 + v1 + v2;
  if (tid == 255) bsum[blockIdx.x] = sd[255];
}

__global__ void scan2(int* bsum, int nb) {
  if (threadIdx.x == 0 && blockIdx.x == 0) {
    int run = 0;
    for (int i = 0; i < nb; ++i) { int t = bsum[i]; bsum[i] = run; run += t; }
  }
}

__global__ __launch_bounds__(256) void scan3(int* __restrict__ rp,
                                             const int* __restrict__ bsum,
                                             int* __restrict__ cursor) {
  int base = blockIdx.x * 1024 + threadIdx.x * 4;
  int add = bsum[blockIdx.x];
#pragma unroll
  for (int i = 0; i < 4; ++i) {
    int idx = base + i;
    if (idx < N_NODES) { int v = rp[idx] + add; rp[idx] = v; cursor[idx] = v; }
  }
  if (blockIdx.x == 0 && threadIdx.x == 0) rp[N_NODES] = N_EDGES;
}

__global__ __launch_bounds__(256) void scatter_kernel(const int* __restrict__ src,
                                                      const int* __restrict__ dst,
                                                      int* __restrict__ cursor,
                                                      int* __restrict__ ci) {
  int i = blockIdx.x * blockDim.x + threadIdx.x;
  for (; i < N_EDGES; i += gridDim.x * blockDim.x) {
    int d = dst[i];
    int p = atomicAdd(&cursor[d], 1);
    ci[p] = src[i];
  }
}

// ---------------- aggregation: out[i] = h[i] + sum_{e in row i} h[ci[e]] ----------------
__global__ __launch_bounds__(256) void agg_kernel(const float* __restrict__ hin,
                                                  const int* __restrict__ rp,
                                                  const int* __restrict__ ci,
                                                  float* __restrict__ out) {
  int wid = (blockIdx.x * blockDim.x + threadIdx.x) >> 6;
  int lane = threadIdx.x & 63;
  if (wid >= N_NODES) return;
  int beg = rp[wid];
  int end = rp[wid + 1];
  float a0 = hin[wid * 64 + lane];
  float a1 = 0.f, a2 = 0.f, a3 = 0.f;
  int e = beg;
  for (; e + 4 <= end; e += 4) {
    int s0 = ci[e + 0];
    int s1 = ci[e + 1];
    int s2 = ci[e + 2];
    int s3 = ci[e + 3];
    a0 += hin[s0 * 64 + lane];
    a1 += hin[s1 * 64 + lane];
    a2 += hin[s2 * 64 + lane];
    a3 += hin[s3 * 64 + lane];
  }
  for (; e < end; ++e) a1 += hin[ci[e] * 64 + lane];
  out[wid * 64 + lane] = (a0 + a1) + (a2 + a3);
}

// ---------------- x @ W0a (128 -> 64), no bias ----------------
__global__ __launch_bounds__(128) void proj_kernel(const float* __restrict__ x,
                                                   const float* __restrict__ W0a,
                                                   float* __restrict__ out) {
  __shared__ float lds[128 * 65];
  int tid = threadIdx.x;
  int nbase = blockIdx.x * 128;
  float acc[64];
#pragma unroll
  for (int d = 0; d < 64; ++d) acc[d] = 0.f;
#pragma unroll
  for (int ph = 0; ph < 2; ++ph) {
    __syncthreads();
    for (int j = tid; j < 128 * 64; j += 128) {
      int node = j >> 6, col = j & 63;
      float v = (nbase + node < N_NODES) ? x[(nbase + node) * 128 + ph * 64 + col] : 0.f;
      lds[node * 65 + col] = v;
    }
    __syncthreads();
#pragma unroll 4
    for (int k = 0; k < 64; ++k) {
      float zk = lds[tid * 65 + k];
      const float* wr = W0a + (ph * 64 + k) * 64;
#pragma unroll
      for (int d = 0; d < 64; ++d) acc[d] = fmaf(zk, wr[d], acc[d]);
    }
  }
  __syncthreads();
#pragma unroll
  for (int d = 0; d < 64; ++d) lds[tid * 65 + d] = acc[d];
  __syncthreads();
  for (int j = tid; j < 128 * 64; j += 128) {
    int node = nbase + (j >> 6);
    if (node < N_NODES) out[node * 64 + (j & 63)] = lds[(j >> 6) * 65 + (j & 63)];
  }
}

// ---------------- conv0 tail: z_pre -> +b0a, BN, relu, @W0b + b0b, relu ----------------
__global__ __launch_bounds__(128) void mlp0_kernel(const float* __restrict__ zin,
                                                   const float* __restrict__ ba,
                                                   const float* __restrict__ g,
                                                   const float* __restrict__ be,
                                                   const float* __restrict__ Wb,
                                                   const float* __restrict__ bb,
                                                   float* __restrict__ out) {
  __shared__ float lds[128 * 65];
  int tid = threadIdx.x;
  int nbase = blockIdx.x * 128;
  // stage + fused elementwise: t = relu(((z + ba) * C) * g + be)
  for (int j = tid; j < 128 * 64; j += 128) {
    int node = j >> 6, col = j & 63;
    float v = (nbase + node < N_NODES) ? zin[(nbase + node) * 64 + col] : 0.f;
    float t = fmaf((v + ba[col]) * BN_SCALE, g[col], be[col]);
    lds[node * 65 + col] = relu(t);
  }
  __syncthreads();
  float acc[64];
#pragma unroll
  for (int d = 0; d < 64; ++d) acc[d] = bb[d];
#pragma unroll 4
  for (int k = 0; k < 64; ++k) {
    float zk = lds[tid * 65 + k];
    const float* wr = Wb + k * 64;
#pragma unroll
    for (int d = 0; d < 64; ++d) acc[d] = fmaf(zk, wr[d], acc[d]);
  }
  // coalesced write-out via LDS
  __syncthreads();
#pragma unroll
  for (int d = 0; d < 64; ++d) lds[tid * 65 + d] = relu(acc[d]);
  __syncthreads();
  for (int j = tid; j < 128 * 64; j += 128) {
    int node = nbase + (j >> 6);
    if (node < N_NODES) out[node * 64 + (j & 63)] = lds[(j >> 6) * 65 + (j & 63)];
  }
}

// ---------------- convs 1,2: z_pre -> @Wa+ba, BN, relu, @Wb+bb, relu ----------------
__global__ __launch_bounds__(128) void mlp2_kernel(const float* __restrict__ zin,
                                                   const float* __restrict__ Wa,
                                                   const float* __restrict__ ba,
                                                   const float* __restrict__ g,
                                                   const float* __restrict__ be,
                                                   const float* __restrict__ Wb,
                                                   const float* __restrict__ bb,
                                                   float* __restrict__ out) {
  __shared__ float lds[128 * 65];
  int tid = threadIdx.x;
  int nbase = blockIdx.x * 128;
  for (int j = tid; j < 128 * 64; j += 128) {
    int node = j >> 6, col = j & 63;
    float v = (nbase + node < N_NODES) ? zin[(nbase + node) * 64 + col] : 0.f;
    lds[node * 65 + col] = v;
  }
  __syncthreads();
  float acc[64];
#pragma unroll
  for (int d = 0; d < 64; ++d) acc[d] = ba[d];
#pragma unroll 4
  for (int k = 0; k < 64; ++k) {
    float zk = lds[tid * 65 + k];
    const float* wr = Wa + k * 64;
#pragma unroll
    for (int d = 0; d < 64; ++d) acc[d] = fmaf(zk, wr[d], acc[d]);
  }
  // BN + relu back into own LDS row (no barrier needed: own row only)
#pragma unroll
  for (int d = 0; d < 64; ++d) {
    float t = fmaf(acc[d] * BN_SCALE, g[d], be[d]);
    lds[tid * 65 + d] = relu(t);
  }
#pragma unroll
  for (int d = 0; d < 64; ++d) acc[d] = bb[d];
#pragma unroll 4
  for (int k = 0; k < 64; ++k) {
    float zk = lds[tid * 65 + k];
    const float* wr = Wb + k * 64;
#pragma unroll
    for (int d = 0; d < 64; ++d) acc[d] = fmaf(zk, wr[d], acc[d]);
  }
  __syncthreads();
#pragma unroll
  for (int d = 0; d < 64; ++d) lds[tid * 65 + d] = relu(acc[d]);
  __syncthreads();
  for (int j = tid; j < 128 * 64; j += 128) {
    int node = nbase + (j >> 6);
    if (node < N_NODES) out[node * 64 + (j & 63)] = lds[(j >> 6) * 65 + (j & 63)];
  }
}

// ---------------- pool: hp[g] = sum_{batch[n]==g} h[n]; batch is sorted ----------------
__global__ __launch_bounds__(256) void pool_kernel(const float* __restrict__ h,
                                                   const int* __restrict__ batch,
                                                   float* __restrict__ hp) {
  const int CH = (N_NODES + 1023) / 1024;  // 98 nodes per wave
  int w = (blockIdx.x * blockDim.x + threadIdx.x) >> 6;
  int lane = threadIdx.x & 63;
  int start = w * CH;
  if (start >= N_NODES) return;
  int end = start + CH;
  if (end > N_NODES) end = N_NODES;
  int cur = batch[start];
  float acc = 0.f;
  for (int n = start; n < end; ++n) {
    int b = batch[n];
    if (b != cur) {
      atomicAdd(&hp[cur * 64 + lane], acc);
      acc = 0.f;
      cur = b;
    }
    acc += h[n * 64 + lane];
  }
  atomicAdd(&hp[cur * 64 + lane], acc);
}

// ---------------- classifier: relu(hp @ (W1a+W1b+W1c) + bl1) @ Wl2 + bl2, log_softmax ----------------
__global__ void cls_kernel(const float* __restrict__ hp, const float* __restrict__ Wl1,
                           const float* __restrict__ bl1, const float* __restrict__ Wl2,
                           const float* __restrict__ bl2, float* __restrict__ out) {
  int gId = threadIdx.x;  // 64 threads, one per graph
  float z1[64];
#pragma unroll
  for (int d = 0; d < 64; ++d) z1[d] = bl1[d];
  for (int k = 0; k < 64; ++k) {
    float v = hp[gId * 64 + k];
    const float* w0 = Wl1 + k * 64;
    const float* w1 = Wl1 + (64 + k) * 64;
    const float* w2 = Wl1 + (128 + k) * 64;
#pragma unroll
    for (int d = 0; d < 64; ++d) z1[d] = fmaf(v, w0[d] + w1[d] + w2[d], z1[d]);
  }
  float z2_0 = bl2[0], z2_1 = bl2[1];
#pragma unroll
  for (int d = 0; d < 64; ++d) {
    float t = relu(z1[d]);
    z2_0 = fmaf(t, Wl2[d * 2 + 0], z2_0);
    z2_1 = fmaf(t, Wl2[d * 2 + 1], z2_1);
  }
  float m = fmaxf(z2_0, z2_1);
  float lse = m + logf(expf(z2_0 - m) + expf(z2_1 - m));
  out[gId * 2 + 0] = z2_0 - lse;
  out[gId * 2 + 1] = z2_1 - lse;
}

extern "C" void kernel_launch(void* const* d_in, const int* in_sizes, int n_in,
                              void* d_out, int out_size, void* d_ws, size_t ws_size,
                              hipStream_t stream) {
  const float* x   = (const float*)d_in[0];
  const int*   ei  = (const int*)d_in[1];
  const int*   bat = (const int*)d_in[2];
  const float* W0a = (const float*)d_in[3];
  const float* b0a = (const float*)d_in[4];
  const float* g0  = (const float*)d_in[5];
  const float* be0 = (const float*)d_in[6];
  const float* W0b = (const float*)d_in[7];
  const float* b0b = (const float*)d_in[8];
  const float* Wsa = (const float*)d_in[9];
  const float* bsa = (const float*)d_in[10];
  const float* gs  = (const float*)d_in[11];
  const float* bes = (const float*)d_in[12];
  const float* Wsb = (const float*)d_in[13];
  const float* bsb = (const float*)d_in[14];
  const float* Wl1 = (const float*)d_in[15];
  const float* bl1 = (const float*)d_in[16];
  const float* Wl2 = (const float*)d_in[17];
  const float* bl2 = (const float*)d_in[18];
  const int* src = ei;
  const int* dst = ei + N_EDGES;

  char* ws = (char*)d_ws;
  size_t off = 0;
  auto alloc = [&](size_t bytes) { void* p = ws + off; off += (bytes + 255) & ~255ull; return p; };
  int* rp     = (int*)alloc((size_t)(N_NODES + 1) * 4);
  int* cnt    = (int*)alloc((size_t)N_NODES * 4);         // histogram, then cursor
  int* bsum   = (int*)alloc(1024);
  int* ci     = (int*)alloc((size_t)N_EDGES * 4);
  float* bufA = (float*)alloc((size_t)N_NODES * 64 * 4);  // h
  float* bufZ = (float*)alloc((size_t)N_NODES * 64 * 4);  // h + agg
  float* hp   = (float*)alloc((size_t)N_GRAPHS * 64 * 4);

  hipMemsetAsync(cnt, 0, (size_t)N_NODES * 4, stream);
  hipMemsetAsync(hp, 0, (size_t)N_GRAPHS * 64 * 4, stream);

  const int NB = (N_NODES + 1023) / 1024;  // 98
  hist_kernel<<<2048, 256, 0, stream>>>(dst, cnt);
  scan1<<<NB, 256, 0, stream>>>(cnt, rp, bsum);
  scan2<<<1, 64, 0, stream>>>(bsum, NB);
  scan3<<<NB, 256, 0, stream>>>(rp, bsum, cnt);
  scatter_kernel<<<2048, 256, 0, stream>>>(src, dst, cnt, ci);

  const int MB = (N_NODES + 127) / 128;    // 782
  const int AB = (N_NODES + 3) / 4;        // 25000 blocks of 4 waves

  // conv0: project first (linearity), aggregate in 64-dim
  proj_kernel<<<MB, 128, 0, stream>>>(x, W0a, bufA);
  agg_kernel<<<AB, 256, 0, stream>>>(bufA, rp, ci, bufZ);
  mlp0_kernel<<<MB, 128, 0, stream>>>(bufZ, b0a, g0, be0, W0b, b0b, bufA);

  for (int l = 0; l < 2; ++l) {
    agg_kernel<<<AB, 256, 0, stream>>>(bufA, rp, ci, bufZ);
    mlp2_kernel<<<MB, 128, 0, stream>>>(bufZ, Wsa + l * 4096, bsa + l * 64, gs + l * 64,
                                        bes + l * 64, Wsb + l * 4096, bsb + l * 64, bufA);
  }

  pool_kernel<<<256, 256, 0, stream>>>(bufA, bat, hp);
  cls_kernel<<<1, 64, 0, stream>>>(hp, Wl1, bl1, Wl2, bl2, (float*)d_out);
}

// Round 2
// 796.954 us; speedup vs baseline: 1.0287x; 1.0287x over previous
//
#include <hip/hip_runtime.h>

#define N_NODES 100000
#define N_EDGES 1600000
#define IN_DIM 128
#define DIM_H 64
#define N_GRAPHS 64

#define BKT_BITS 9
#define BKT_SIZE 512                       /* nodes per bucket */
#define NBUCKET ((N_NODES + BKT_SIZE - 1) / BKT_SIZE)  /* 196 */
#define BKT_CAP 10240                      /* mean 8163, sigma ~90 -> 23 sigma headroom */

__device__ __forceinline__ float relu(float v) { return v > 0.f ? v : 0.f; }
#define BN_SCALE 0.99999500003749968f  /* 1/sqrt(1+1e-5) */

// ---------------- CSR build: two-level counting sort by dst ----------------
// Pass A: scatter edges into per-bucket arrays (coalesced-ish sequential streams).
__global__ __launch_bounds__(256) void bucket_scatter(const int* __restrict__ src,
                                                      const int* __restrict__ dst,
                                                      int* __restrict__ cur,   // stride-16 padded
                                                      int* __restrict__ bktbuf) {
  int i = blockIdx.x * blockDim.x + threadIdx.x;
  for (; i < N_EDGES; i += gridDim.x * blockDim.x) {
    int d = dst[i];
    int b = d >> BKT_BITS;
    int pos = atomicAdd(&cur[b * 16], 1);
    bktbuf[b * BKT_CAP + pos] = src[i] | ((d & (BKT_SIZE - 1)) << 17);
  }
}

// Scan bucket counts -> bucket bases (196 values, one block).
__global__ void bkt_scan(const int* __restrict__ cur, int* __restrict__ base) {
  __shared__ int sd[256];
  int tid = threadIdx.x;
  int v = (tid < NBUCKET) ? cur[tid * 16] : 0;
  sd[tid] = v;
  __syncthreads();
  for (int off = 1; off < 256; off <<= 1) {
    int t = (tid >= off) ? sd[tid - off] : 0;
    __syncthreads();
    sd[tid] += t;
    __syncthreads();
  }
  if (tid < NBUCKET) base[tid] = sd[tid] - v;
}

// Pass B: per-bucket local counting sort; emits rp[] and ci[].
__global__ __launch_bounds__(256) void bucket_sort(const int* __restrict__ cur,
                                                   const int* __restrict__ bktbase,
                                                   const int* __restrict__ bktbuf,
                                                   int* __restrict__ rp,
                                                   int* __restrict__ ci) {
  __shared__ int hist[BKT_SIZE];
  __shared__ int partial[256];
  int b = blockIdx.x;
  int tid = threadIdx.x;
  int nb = cur[b * 16];
  int base = bktbase[b];
  const int* buf = bktbuf + (size_t)b * BKT_CAP;
  hist[tid] = 0;
  hist[tid + 256] = 0;
  __syncthreads();
  for (int i = tid; i < nb; i += 256) atomicAdd(&hist[buf[i] >> 17], 1);
  __syncthreads();
  int v0 = hist[2 * tid], v1 = hist[2 * tid + 1];
  int s = v0 + v1;
  partial[tid] = s;
  __syncthreads();
  for (int off = 1; off < 256; off <<= 1) {
    int t = (tid >= off) ? partial[tid - off] : 0;
    __syncthreads();
    partial[tid] += t;
    __syncthreads();
  }
  int excl = partial[tid] - s;
  int node0 = b * BKT_SIZE + 2 * tid;
  if (node0 < N_NODES) rp[node0] = base + excl;
  if (node0 + 1 < N_NODES) rp[node0 + 1] = base + excl + v0;
  hist[2 * tid] = excl;          // reuse as local cursor
  hist[2 * tid + 1] = excl + v0;
  __syncthreads();
  for (int i = tid; i < nb; i += 256) {
    int p = buf[i];
    int pos = atomicAdd(&hist[p >> 17], 1);
    ci[base + pos] = p & 0x1FFFF;
  }
  if (b == 0 && tid == 0) rp[N_NODES] = N_EDGES;
}

// ---------------- aggregation: out[i] = h[i] + sum_{e in row i} h[ci[e]] ----------------
__global__ __launch_bounds__(256) void agg_kernel(const float* __restrict__ hin,
                                                  const int* __restrict__ rp,
                                                  const int* __restrict__ ci,
                                                  float* __restrict__ out) {
  int wid = (blockIdx.x * blockDim.x + threadIdx.x) >> 6;
  int lane = threadIdx.x & 63;
  if (wid >= N_NODES) return;
  int beg = rp[wid];
  int end = rp[wid + 1];
  float a0 = hin[wid * 64 + lane];
  float a1 = 0.f, a2 = 0.f, a3 = 0.f;
  int e = beg;
  for (; e + 4 <= end; e += 4) {
    int s0 = ci[e + 0];
    int s1 = ci[e + 1];
    int s2 = ci[e + 2];
    int s3 = ci[e + 3];
    a0 += hin[s0 * 64 + lane];
    a1 += hin[s1 * 64 + lane];
    a2 += hin[s2 * 64 + lane];
    a3 += hin[s3 * 64 + lane];
  }
  for (; e < end; ++e) a1 += hin[ci[e] * 64 + lane];
  out[wid * 64 + lane] = (a0 + a1) + (a2 + a3);
}

// ---------------- x @ W0a (128 -> 64), no bias ----------------
__global__ __launch_bounds__(128) void proj_kernel(const float* __restrict__ x,
                                                   const float* __restrict__ W0a,
                                                   float* __restrict__ out) {
  __shared__ float lds[128 * 65];
  int tid = threadIdx.x;
  int nbase = blockIdx.x * 128;
  float acc[64];
#pragma unroll
  for (int d = 0; d < 64; ++d) acc[d] = 0.f;
#pragma unroll
  for (int ph = 0; ph < 2; ++ph) {
    __syncthreads();
    for (int j = tid; j < 128 * 64; j += 128) {
      int node = j >> 6, col = j & 63;
      float v = (nbase + node < N_NODES) ? x[(nbase + node) * 128 + ph * 64 + col] : 0.f;
      lds[node * 65 + col] = v;
    }
    __syncthreads();
#pragma unroll 4
    for (int k = 0; k < 64; ++k) {
      float zk = lds[tid * 65 + k];
      const float* wr = W0a + (ph * 64 + k) * 64;
#pragma unroll
      for (int d = 0; d < 64; ++d) acc[d] = fmaf(zk, wr[d], acc[d]);
    }
  }
  __syncthreads();
#pragma unroll
  for (int d = 0; d < 64; ++d) lds[tid * 65 + d] = acc[d];
  __syncthreads();
  for (int j = tid; j < 128 * 64; j += 128) {
    int node = nbase + (j >> 6);
    if (node < N_NODES) out[node * 64 + (j & 63)] = lds[(j >> 6) * 65 + (j & 63)];
  }
}

// ---------------- conv0 tail: z_pre -> +b0a, BN, relu, @W0b + b0b, relu ----------------
__global__ __launch_bounds__(128) void mlp0_kernel(const float* __restrict__ zin,
                                                   const float* __restrict__ ba,
                                                   const float* __restrict__ g,
                                                   const float* __restrict__ be,
                                                   const float* __restrict__ Wb,
                                                   const float* __restrict__ bb,
                                                   float* __restrict__ out) {
  __shared__ float lds[128 * 65];
  int tid = threadIdx.x;
  int nbase = blockIdx.x * 128;
  for (int j = tid; j < 128 * 64; j += 128) {
    int node = j >> 6, col = j & 63;
    float v = (nbase + node < N_NODES) ? zin[(nbase + node) * 64 + col] : 0.f;
    float t = fmaf((v + ba[col]) * BN_SCALE, g[col], be[col]);
    lds[node * 65 + col] = relu(t);
  }
  __syncthreads();
  float acc[64];
#pragma unroll
  for (int d = 0; d < 64; ++d) acc[d] = bb[d];
#pragma unroll 4
  for (int k = 0; k < 64; ++k) {
    float zk = lds[tid * 65 + k];
    const float* wr = Wb + k * 64;
#pragma unroll
    for (int d = 0; d < 64; ++d) acc[d] = fmaf(zk, wr[d], acc[d]);
  }
  __syncthreads();
#pragma unroll
  for (int d = 0; d < 64; ++d) lds[tid * 65 + d] = relu(acc[d]);
  __syncthreads();
  for (int j = tid; j < 128 * 64; j += 128) {
    int node = nbase + (j >> 6);
    if (node < N_NODES) out[node * 64 + (j & 63)] = lds[(j >> 6) * 65 + (j & 63)];
  }
}

// ---------------- convs 1,2: z_pre -> @Wa+ba, BN, relu, @Wb+bb, relu ----------------
__global__ __launch_bounds__(128) void mlp2_kernel(const float* __restrict__ zin,
                                                   const float* __restrict__ Wa,
                                                   const float* __restrict__ ba,
                                                   const float* __restrict__ g,
                                                   const float* __restrict__ be,
                                                   const float* __restrict__ Wb,
                                                   const float* __restrict__ bb,
                                                   float* __restrict__ out) {
  __shared__ float lds[128 * 65];
  int tid = threadIdx.x;
  int nbase = blockIdx.x * 128;
  for (int j = tid; j < 128 * 64; j += 128) {
    int node = j >> 6, col = j & 63;
    float v = (nbase + node < N_NODES) ? zin[(nbase + node) * 64 + col] : 0.f;
    lds[node * 65 + col] = v;
  }
  __syncthreads();
  float acc[64];
#pragma unroll
  for (int d = 0; d < 64; ++d) acc[d] = ba[d];
#pragma unroll 4
  for (int k = 0; k < 64; ++k) {
    float zk = lds[tid * 65 + k];
    const float* wr = Wa + k * 64;
#pragma unroll
    for (int d = 0; d < 64; ++d) acc[d] = fmaf(zk, wr[d], acc[d]);
  }
#pragma unroll
  for (int d = 0; d < 64; ++d) {
    float t = fmaf(acc[d] * BN_SCALE, g[d], be[d]);
    lds[tid * 65 + d] = relu(t);
  }
#pragma unroll
  for (int d = 0; d < 64; ++d) acc[d] = bb[d];
#pragma unroll 4
  for (int k = 0; k < 64; ++k) {
    float zk = lds[tid * 65 + k];
    const float* wr = Wb + k * 64;
#pragma unroll
    for (int d = 0; d < 64; ++d) acc[d] = fmaf(zk, wr[d], acc[d]);
  }
  __syncthreads();
#pragma unroll
  for (int d = 0; d < 64; ++d) lds[tid * 65 + d] = relu(acc[d]);
  __syncthreads();
  for (int j = tid; j < 128 * 64; j += 128) {
    int node = nbase + (j >> 6);
    if (node < N_NODES) out[node * 64 + (j & 63)] = lds[(j >> 6) * 65 + (j & 63)];
  }
}

// ---------------- pool: hp[g] = sum_{batch[n]==g} h[n]; batch is sorted ----------------
__global__ __launch_bounds__(256) void pool_kernel(const float* __restrict__ h,
                                                   const int* __restrict__ batch,
                                                   float* __restrict__ hp) {
  const int CH = (N_NODES + 1023) / 1024;
  int w = (blockIdx.x * blockDim.x + threadIdx.x) >> 6;
  int lane = threadIdx.x & 63;
  int start = w * CH;
  if (start >= N_NODES) return;
  int end = start + CH;
  if (end > N_NODES) end = N_NODES;
  int cur = batch[start];
  float acc = 0.f;
  for (int n = start; n < end; ++n) {
    int b = batch[n];
    if (b != cur) {
      atomicAdd(&hp[cur * 64 + lane], acc);
      acc = 0.f;
      cur = b;
    }
    acc += h[n * 64 + lane];
  }
  atomicAdd(&hp[cur * 64 + lane], acc);
}

// ---------------- classifier ----------------
__global__ void cls_kernel(const float* __restrict__ hp, const float* __restrict__ Wl1,
                           const float* __restrict__ bl1, const float* __restrict__ Wl2,
                           const float* __restrict__ bl2, float* __restrict__ out) {
  int gId = threadIdx.x;
  float z1[64];
#pragma unroll
  for (int d = 0; d < 64; ++d) z1[d] = bl1[d];
  for (int k = 0; k < 64; ++k) {
    float v = hp[gId * 64 + k];
    const float* w0 = Wl1 + k * 64;
    const float* w1 = Wl1 + (64 + k) * 64;
    const float* w2 = Wl1 + (128 + k) * 64;
#pragma unroll
    for (int d = 0; d < 64; ++d) z1[d] = fmaf(v, w0[d] + w1[d] + w2[d], z1[d]);
  }
  float z2_0 = bl2[0], z2_1 = bl2[1];
#pragma unroll
  for (int d = 0; d < 64; ++d) {
    float t = relu(z1[d]);
    z2_0 = fmaf(t, Wl2[d * 2 + 0], z2_0);
    z2_1 = fmaf(t, Wl2[d * 2 + 1], z2_1);
  }
  float m = fmaxf(z2_0, z2_1);
  float lse = m + logf(expf(z2_0 - m) + expf(z2_1 - m));
  out[gId * 2 + 0] = z2_0 - lse;
  out[gId * 2 + 1] = z2_1 - lse;
}

extern "C" void kernel_launch(void* const* d_in, const int* in_sizes, int n_in,
                              void* d_out, int out_size, void* d_ws, size_t ws_size,
                              hipStream_t stream) {
  const float* x   = (const float*)d_in[0];
  const int*   ei  = (const int*)d_in[1];
  const int*   bat = (const int*)d_in[2];
  const float* W0a = (const float*)d_in[3];
  const float* b0a = (const float*)d_in[4];
  const float* g0  = (const float*)d_in[5];
  const float* be0 = (const float*)d_in[6];
  const float* W0b = (const float*)d_in[7];
  const float* b0b = (const float*)d_in[8];
  const float* Wsa = (const float*)d_in[9];
  const float* bsa = (const float*)d_in[10];
  const float* gs  = (const float*)d_in[11];
  const float* bes = (const float*)d_in[12];
  const float* Wsb = (const float*)d_in[13];
  const float* bsb = (const float*)d_in[14];
  const float* Wl1 = (const float*)d_in[15];
  const float* bl1 = (const float*)d_in[16];
  const float* Wl2 = (const float*)d_in[17];
  const float* bl2 = (const float*)d_in[18];
  const int* src = ei;
  const int* dst = ei + N_EDGES;

  char* ws = (char*)d_ws;
  size_t off = 0;
  auto alloc = [&](size_t bytes) { void* p = ws + off; off += (bytes + 255) & ~255ull; return p; };
  int* rp      = (int*)alloc((size_t)(N_NODES + 1) * 4);
  int* bktcur  = (int*)alloc((size_t)NBUCKET * 16 * 4);  // stride-16 padded counters
  int* bktbase = (int*)alloc((size_t)NBUCKET * 4);
  int* ci      = (int*)alloc((size_t)N_EDGES * 4);
  float* bufA  = (float*)alloc((size_t)N_NODES * 64 * 4);
  float* bufZ  = (float*)alloc((size_t)N_NODES * 64 * 4);
  float* hp    = (float*)alloc((size_t)N_GRAPHS * 64 * 4);
  int* bktbuf  = (int*)bufZ;  // alias: bucket buffer (8 MB) consumed before bufZ first written

  hipMemsetAsync(bktcur, 0, (size_t)NBUCKET * 16 * 4, stream);
  hipMemsetAsync(hp, 0, (size_t)N_GRAPHS * 64 * 4, stream);

  bucket_scatter<<<2048, 256, 0, stream>>>(src, dst, bktcur, bktbuf);
  bkt_scan<<<1, 256, 0, stream>>>(bktcur, bktbase);
  bucket_sort<<<NBUCKET, 256, 0, stream>>>(bktcur, bktbase, bktbuf, rp, ci);

  const int MB = (N_NODES + 127) / 128;    // 782
  const int AB = (N_NODES + 3) / 4;        // 25000 blocks of 4 waves

  proj_kernel<<<MB, 128, 0, stream>>>(x, W0a, bufA);
  agg_kernel<<<AB, 256, 0, stream>>>(bufA, rp, ci, bufZ);
  mlp0_kernel<<<MB, 128, 0, stream>>>(bufZ, b0a, g0, be0, W0b, b0b, bufA);

  for (int l = 0; l < 2; ++l) {
    agg_kernel<<<AB, 256, 0, stream>>>(bufA, rp, ci, bufZ);
    mlp2_kernel<<<MB, 128, 0, stream>>>(bufZ, Wsa + l * 4096, bsa + l * 64, gs + l * 64,
                                        bes + l * 64, Wsb + l * 4096, bsb + l * 64, bufA);
  }

  pool_kernel<<<256, 256, 0, stream>>>(bufA, bat, hp);
  cls_kernel<<<1, 64, 0, stream>>>(hp, Wl1, bl1, Wl2, bl2, (float*)d_out);
}

// Round 3
// 665.609 us; speedup vs baseline: 1.2317x; 1.1973x over previous
//
#include <hip/hip_runtime.h>

#define N_NODES 100000
#define N_EDGES 1600000
#define IN_DIM 128
#define DIM_H 64
#define N_GRAPHS 64

#define BKT_BITS 9
#define BKT_SIZE 512
#define NBUCKET ((N_NODES + BKT_SIZE - 1) / BKT_SIZE)  /* 196 */
#define NBLK 256
#define EPB ((N_EDGES + NBLK - 1) / NBLK)              /* 6250 */

__device__ __forceinline__ float relu(float v) { return v > 0.f ? v : 0.f; }
#define BN_SCALE 0.99999500003749968f  /* 1/sqrt(1+1e-5) */

// ---------------- CSR build: 3-phase block-private counting sort ----------------
// Phase 1: per-block histogram over buckets (LDS only).
__global__ __launch_bounds__(256) void edge_count(const int* __restrict__ dst,
                                                  int* __restrict__ cnt) {
  __shared__ int hist[NBUCKET];
  int tid = threadIdx.x, blk = blockIdx.x;
  if (tid < NBUCKET) hist[tid] = 0;
  __syncthreads();
  int beg = blk * EPB, end = beg + EPB > N_EDGES ? N_EDGES : beg + EPB;
  for (int i = beg + tid; i < end; i += 256) atomicAdd(&hist[dst[i] >> BKT_BITS], 1);
  __syncthreads();
  if (tid < NBUCKET) cnt[blk * NBUCKET + tid] = hist[tid];
}

// Phase 2a: per-bucket exclusive scan over blocks (in-place), emit per-bucket totals.
__global__ __launch_bounds__(256) void col_scan(int* __restrict__ cnt,
                                                int* __restrict__ tot) {
  __shared__ int sd[NBLK];
  int b = blockIdx.x, tid = threadIdx.x;
  int v = cnt[tid * NBUCKET + b];
  sd[tid] = v;
  __syncthreads();
  for (int off = 1; off < NBLK; off <<= 1) {
    int t = (tid >= off) ? sd[tid - off] : 0;
    __syncthreads();
    sd[tid] += t;
    __syncthreads();
  }
  cnt[tid * NBUCKET + b] = sd[tid] - v;
  if (tid == NBLK - 1) tot[b] = sd[tid];
}

// Phase 2b: exclusive scan over bucket totals -> bucket bases.
__global__ void base_scan(const int* __restrict__ tot, int* __restrict__ base) {
  __shared__ int sd[256];
  int tid = threadIdx.x;
  int v = (tid < NBUCKET) ? tot[tid] : 0;
  sd[tid] = v;
  __syncthreads();
  for (int off = 1; off < 256; off <<= 1) {
    int t = (tid >= off) ? sd[tid - off] : 0;
    __syncthreads();
    sd[tid] += t;
    __syncthreads();
  }
  if (tid < NBUCKET) base[tid] = sd[tid] - v;
}

// Phase 3: place edges into block-private sequential segments (LDS cursors, no global atomics).
__global__ __launch_bounds__(256) void edge_place(const int* __restrict__ src,
                                                  const int* __restrict__ dst,
                                                  const int* __restrict__ cnt,
                                                  const int* __restrict__ base,
                                                  int* __restrict__ bktbuf) {
  __shared__ int curs[NBUCKET];
  int tid = threadIdx.x, blk = blockIdx.x;
  if (tid < NBUCKET) curs[tid] = base[tid] + cnt[blk * NBUCKET + tid];
  __syncthreads();
  int beg = blk * EPB, end = beg + EPB > N_EDGES ? N_EDGES : beg + EPB;
  for (int i = beg + tid; i < end; i += 256) {
    int d = dst[i];
    int b = d >> BKT_BITS;
    int pos = atomicAdd(&curs[b], 1);
    bktbuf[pos] = src[i] | ((d & (BKT_SIZE - 1)) << 17);
  }
}

// Phase 4: per-bucket local counting sort; emits rp[] and ci[].
__global__ __launch_bounds__(256) void bucket_sort(const int* __restrict__ tot,
                                                   const int* __restrict__ bktbase,
                                                   const int* __restrict__ bktbuf,
                                                   int* __restrict__ rp,
                                                   int* __restrict__ ci) {
  __shared__ int hist[BKT_SIZE];
  __shared__ int partial[256];
  int b = blockIdx.x;
  int tid = threadIdx.x;
  int nb = tot[b];
  int base = bktbase[b];
  const int* buf = bktbuf + base;
  hist[tid] = 0;
  hist[tid + 256] = 0;
  __syncthreads();
  for (int i = tid; i < nb; i += 256) atomicAdd(&hist[buf[i] >> 17], 1);
  __syncthreads();
  int v0 = hist[2 * tid], v1 = hist[2 * tid + 1];
  int s = v0 + v1;
  partial[tid] = s;
  __syncthreads();
  for (int off = 1; off < 256; off <<= 1) {
    int t = (tid >= off) ? partial[tid - off] : 0;
    __syncthreads();
    partial[tid] += t;
    __syncthreads();
  }
  int excl = partial[tid] - s;
  int node0 = b * BKT_SIZE + 2 * tid;
  if (node0 < N_NODES) rp[node0] = base + excl;
  if (node0 + 1 < N_NODES) rp[node0 + 1] = base + excl + v0;
  __syncthreads();
  hist[2 * tid] = excl;          // reuse as local cursor
  hist[2 * tid + 1] = excl + v0;
  __syncthreads();
  for (int i = tid; i < nb; i += 256) {
    int p = buf[i];
    int pos = atomicAdd(&hist[p >> 17], 1);
    ci[base + pos] = p & 0x1FFFF;
  }
  if (b == 0 && tid == 0) rp[N_NODES] = N_EDGES;
}

// ---------------- aggregation: out[i] = h[i] + sum_{e in row i} h[ci[e]] ----------------
__global__ __launch_bounds__(256) void agg_kernel(const float* __restrict__ hin,
                                                  const int* __restrict__ rp,
                                                  const int* __restrict__ ci,
                                                  float* __restrict__ out) {
  int wid = (blockIdx.x * blockDim.x + threadIdx.x) >> 6;
  int lane = threadIdx.x & 63;
  if (wid >= N_NODES) return;
  int beg = rp[wid];
  int end = rp[wid + 1];
  float a0 = hin[wid * 64 + lane];
  float a1 = 0.f, a2 = 0.f, a3 = 0.f;
  int e = beg;
  for (; e + 4 <= end; e += 4) {
    int s0 = ci[e + 0];
    int s1 = ci[e + 1];
    int s2 = ci[e + 2];
    int s3 = ci[e + 3];
    a0 += hin[s0 * 64 + lane];
    a1 += hin[s1 * 64 + lane];
    a2 += hin[s2 * 64 + lane];
    a3 += hin[s3 * 64 + lane];
  }
  for (; e < end; ++e) a1 += hin[ci[e] * 64 + lane];
  out[wid * 64 + lane] = (a0 + a1) + (a2 + a3);
}

// ---------------- x @ W0a (128 -> 64), no bias ----------------
__global__ __launch_bounds__(128) void proj_kernel(const float* __restrict__ x,
                                                   const float* __restrict__ W0a,
                                                   float* __restrict__ out) {
  __shared__ float lds[128 * 65];
  int tid = threadIdx.x;
  int nbase = blockIdx.x * 128;
  float acc[64];
#pragma unroll
  for (int d = 0; d < 64; ++d) acc[d] = 0.f;
#pragma unroll
  for (int ph = 0; ph < 2; ++ph) {
    __syncthreads();
    for (int j = tid; j < 128 * 64; j += 128) {
      int node = j >> 6, col = j & 63;
      float v = (nbase + node < N_NODES) ? x[(nbase + node) * 128 + ph * 64 + col] : 0.f;
      lds[node * 65 + col] = v;
    }
    __syncthreads();
#pragma unroll 4
    for (int k = 0; k < 64; ++k) {
      float zk = lds[tid * 65 + k];
      const float* wr = W0a + (ph * 64 + k) * 64;
#pragma unroll
      for (int d = 0; d < 64; ++d) acc[d] = fmaf(zk, wr[d], acc[d]);
    }
  }
  __syncthreads();
#pragma unroll
  for (int d = 0; d < 64; ++d) lds[tid * 65 + d] = acc[d];
  __syncthreads();
  for (int j = tid; j < 128 * 64; j += 128) {
    int node = nbase + (j >> 6);
    if (node < N_NODES) out[node * 64 + (j & 63)] = lds[(j >> 6) * 65 + (j & 63)];
  }
}

// ---------------- conv0 tail ----------------
__global__ __launch_bounds__(128) void mlp0_kernel(const float* __restrict__ zin,
                                                   const float* __restrict__ ba,
                                                   const float* __restrict__ g,
                                                   const float* __restrict__ be,
                                                   const float* __restrict__ Wb,
                                                   const float* __restrict__ bb,
                                                   float* __restrict__ out) {
  __shared__ float lds[128 * 65];
  int tid = threadIdx.x;
  int nbase = blockIdx.x * 128;
  for (int j = tid; j < 128 * 64; j += 128) {
    int node = j >> 6, col = j & 63;
    float v = (nbase + node < N_NODES) ? zin[(nbase + node) * 64 + col] : 0.f;
    float t = fmaf((v + ba[col]) * BN_SCALE, g[col], be[col]);
    lds[node * 65 + col] = relu(t);
  }
  __syncthreads();
  float acc[64];
#pragma unroll
  for (int d = 0; d < 64; ++d) acc[d] = bb[d];
#pragma unroll 4
  for (int k = 0; k < 64; ++k) {
    float zk = lds[tid * 65 + k];
    const float* wr = Wb + k * 64;
#pragma unroll
    for (int d = 0; d < 64; ++d) acc[d] = fmaf(zk, wr[d], acc[d]);
  }
  __syncthreads();
#pragma unroll
  for (int d = 0; d < 64; ++d) lds[tid * 65 + d] = relu(acc[d]);
  __syncthreads();
  for (int j = tid; j < 128 * 64; j += 128) {
    int node = nbase + (j >> 6);
    if (node < N_NODES) out[node * 64 + (j & 63)] = lds[(j >> 6) * 65 + (j & 63)];
  }
}

// ---------------- convs 1,2 ----------------
__global__ __launch_bounds__(128) void mlp2_kernel(const float* __restrict__ zin,
                                                   const float* __restrict__ Wa,
                                                   const float* __restrict__ ba,
                                                   const float* __restrict__ g,
                                                   const float* __restrict__ be,
                                                   const float* __restrict__ Wb,
                                                   const float* __restrict__ bb,
                                                   float* __restrict__ out) {
  __shared__ float lds[128 * 65];
  int tid = threadIdx.x;
  int nbase = blockIdx.x * 128;
  for (int j = tid; j < 128 * 64; j += 128) {
    int node = j >> 6, col = j & 63;
    float v = (nbase + node < N_NODES) ? zin[(nbase + node) * 64 + col] : 0.f;
    lds[node * 65 + col] = v;
  }
  __syncthreads();
  float acc[64];
#pragma unroll
  for (int d = 0; d < 64; ++d) acc[d] = ba[d];
#pragma unroll 4
  for (int k = 0; k < 64; ++k) {
    float zk = lds[tid * 65 + k];
    const float* wr = Wa + k * 64;
#pragma unroll
    for (int d = 0; d < 64; ++d) acc[d] = fmaf(zk, wr[d], acc[d]);
  }
#pragma unroll
  for (int d = 0; d < 64; ++d) {
    float t = fmaf(acc[d] * BN_SCALE, g[d], be[d]);
    lds[tid * 65 + d] = relu(t);
  }
#pragma unroll
  for (int d = 0; d < 64; ++d) acc[d] = bb[d];
#pragma unroll 4
  for (int k = 0; k < 64; ++k) {
    float zk = lds[tid * 65 + k];
    const float* wr = Wb + k * 64;
#pragma unroll
    for (int d = 0; d < 64; ++d) acc[d] = fmaf(zk, wr[d], acc[d]);
  }
  __syncthreads();
#pragma unroll
  for (int d = 0; d < 64; ++d) lds[tid * 65 + d] = relu(acc[d]);
  __syncthreads();
  for (int j = tid; j < 128 * 64; j += 128) {
    int node = nbase + (j >> 6);
    if (node < N_NODES) out[node * 64 + (j & 63)] = lds[(j >> 6) * 65 + (j & 63)];
  }
}

// ---------------- pool ----------------
__global__ __launch_bounds__(256) void pool_kernel(const float* __restrict__ h,
                                                   const int* __restrict__ batch,
                                                   float* __restrict__ hp) {
  const int CH = (N_NODES + 1023) / 1024;
  int w = (blockIdx.x * blockDim.x + threadIdx.x) >> 6;
  int lane = threadIdx.x & 63;
  int start = w * CH;
  if (start >= N_NODES) return;
  int end = start + CH;
  if (end > N_NODES) end = N_NODES;
  int cur = batch[start];
  float acc = 0.f;
  for (int n = start; n < end; ++n) {
    int b = batch[n];
    if (b != cur) {
      atomicAdd(&hp[cur * 64 + lane], acc);
      acc = 0.f;
      cur = b;
    }
    acc += h[n * 64 + lane];
  }
  atomicAdd(&hp[cur * 64 + lane], acc);
}

// ---------------- classifier ----------------
__global__ void cls_kernel(const float* __restrict__ hp, const float* __restrict__ Wl1,
                           const float* __restrict__ bl1, const float* __restrict__ Wl2,
                           const float* __restrict__ bl2, float* __restrict__ out) {
  int gId = threadIdx.x;
  float z1[64];
#pragma unroll
  for (int d = 0; d < 64; ++d) z1[d] = bl1[d];
  for (int k = 0; k < 64; ++k) {
    float v = hp[gId * 64 + k];
    const float* w0 = Wl1 + k * 64;
    const float* w1 = Wl1 + (64 + k) * 64;
    const float* w2 = Wl1 + (128 + k) * 64;
#pragma unroll
    for (int d = 0; d < 64; ++d) z1[d] = fmaf(v, w0[d] + w1[d] + w2[d], z1[d]);
  }
  float z2_0 = bl2[0], z2_1 = bl2[1];
#pragma unroll
  for (int d = 0; d < 64; ++d) {
    float t = relu(z1[d]);
    z2_0 = fmaf(t, Wl2[d * 2 + 0], z2_0);
    z2_1 = fmaf(t, Wl2[d * 2 + 1], z2_1);
  }
  float m = fmaxf(z2_0, z2_1);
  float lse = m + logf(expf(z2_0 - m) + expf(z2_1 - m));
  out[gId * 2 + 0] = z2_0 - lse;
  out[gId * 2 + 1] = z2_1 - lse;
}

extern "C" void kernel_launch(void* const* d_in, const int* in_sizes, int n_in,
                              void* d_out, int out_size, void* d_ws, size_t ws_size,
                              hipStream_t stream) {
  const float* x   = (const float*)d_in[0];
  const int*   ei  = (const int*)d_in[1];
  const int*   bat = (const int*)d_in[2];
  const float* W0a = (const float*)d_in[3];
  const float* b0a = (const float*)d_in[4];
  const float* g0  = (const float*)d_in[5];
  const float* be0 = (const float*)d_in[6];
  const float* W0b = (const float*)d_in[7];
  const float* b0b = (const float*)d_in[8];
  const float* Wsa = (const float*)d_in[9];
  const float* bsa = (const float*)d_in[10];
  const float* gs  = (const float*)d_in[11];
  const float* bes = (const float*)d_in[12];
  const float* Wsb = (const float*)d_in[13];
  const float* bsb = (const float*)d_in[14];
  const float* Wl1 = (const float*)d_in[15];
  const float* bl1 = (const float*)d_in[16];
  const float* Wl2 = (const float*)d_in[17];
  const float* bl2 = (const float*)d_in[18];
  const int* src = ei;
  const int* dst = ei + N_EDGES;

  char* ws = (char*)d_ws;
  size_t off = 0;
  auto alloc = [&](size_t bytes) { void* p = ws + off; off += (bytes + 255) & ~255ull; return p; };
  int* rp      = (int*)alloc((size_t)(N_NODES + 1) * 4);
  int* cnt     = (int*)alloc((size_t)NBLK * NBUCKET * 4);
  int* tot     = (int*)alloc((size_t)NBUCKET * 4);
  int* bktbase = (int*)alloc((size_t)NBUCKET * 4);
  int* ci      = (int*)alloc((size_t)N_EDGES * 4);
  float* bufA  = (float*)alloc((size_t)N_NODES * 64 * 4);
  float* bufZ  = (float*)alloc((size_t)N_NODES * 64 * 4);
  float* hp    = (float*)alloc((size_t)N_GRAPHS * 64 * 4);
  int* bktbuf  = (int*)bufZ;  // alias: consumed before bufZ first written

  hipMemsetAsync(hp, 0, (size_t)N_GRAPHS * 64 * 4, stream);

  edge_count<<<NBLK, 256, 0, stream>>>(dst, cnt);
  col_scan<<<NBUCKET, NBLK, 0, stream>>>(cnt, tot);
  base_scan<<<1, 256, 0, stream>>>(tot, bktbase);
  edge_place<<<NBLK, 256, 0, stream>>>(src, dst, cnt, bktbase, bktbuf);
  bucket_sort<<<NBUCKET, 256, 0, stream>>>(tot, bktbase, bktbuf, rp, ci);

  const int MB = (N_NODES + 127) / 128;    // 782
  const int AB = (N_NODES + 3) / 4;        // 25000 blocks of 4 waves

  proj_kernel<<<MB, 128, 0, stream>>>(x, W0a, bufA);
  agg_kernel<<<AB, 256, 0, stream>>>(bufA, rp, ci, bufZ);
  mlp0_kernel<<<MB, 128, 0, stream>>>(bufZ, b0a, g0, be0, W0b, b0b, bufA);

  for (int l = 0; l < 2; ++l) {
    agg_kernel<<<AB, 256, 0, stream>>>(bufA, rp, ci, bufZ);
    mlp2_kernel<<<MB, 128, 0, stream>>>(bufZ, Wsa + l * 4096, bsa + l * 64, gs + l * 64,
                                        bes + l * 64, Wsb + l * 4096, bsb + l * 64, bufA);
  }

  pool_kernel<<<256, 256, 0, stream>>>(bufA, bat, hp);
  cls_kernel<<<1, 64, 0, stream>>>(hp, Wl1, bl1, Wl2, bl2, (float*)d_out);
}

// Round 4
// 576.101 us; speedup vs baseline: 1.4231x; 1.1554x over previous
//
#include <hip/hip_runtime.h>

#define N_NODES 100000
#define N_EDGES 1600000
#define IN_DIM 128
#define DIM_H 64
#define N_GRAPHS 64

#define BKT_BITS 9
#define BKT_SIZE 512
#define NBUCKET ((N_NODES + BKT_SIZE - 1) / BKT_SIZE)  /* 196 */
#define NBLK 256
#define EPB ((N_EDGES + NBLK - 1) / NBLK)              /* 6250 */

__device__ __forceinline__ float relu(float v) { return v > 0.f ? v : 0.f; }
#define BN_SCALE 0.99999500003749968f  /* 1/sqrt(1+1e-5) */

// ---------------- CSR build: 3-phase block-private counting sort ----------------
__global__ __launch_bounds__(256) void edge_count(const int* __restrict__ dst,
                                                  int* __restrict__ cnt) {
  __shared__ int hist[NBUCKET];
  int tid = threadIdx.x, blk = blockIdx.x;
  if (tid < NBUCKET) hist[tid] = 0;
  __syncthreads();
  int beg = blk * EPB, end = beg + EPB > N_EDGES ? N_EDGES : beg + EPB;
  for (int i = beg + tid; i < end; i += 256) atomicAdd(&hist[dst[i] >> BKT_BITS], 1);
  __syncthreads();
  if (tid < NBUCKET) cnt[blk * NBUCKET + tid] = hist[tid];
}

__global__ __launch_bounds__(256) void col_scan(int* __restrict__ cnt,
                                                int* __restrict__ tot) {
  __shared__ int sd[NBLK];
  int b = blockIdx.x, tid = threadIdx.x;
  int v = cnt[tid * NBUCKET + b];
  sd[tid] = v;
  __syncthreads();
  for (int off = 1; off < NBLK; off <<= 1) {
    int t = (tid >= off) ? sd[tid - off] : 0;
    __syncthreads();
    sd[tid] += t;
    __syncthreads();
  }
  cnt[tid * NBUCKET + b] = sd[tid] - v;
  if (tid == NBLK - 1) tot[b] = sd[tid];
}

__global__ void base_scan(const int* __restrict__ tot, int* __restrict__ base) {
  __shared__ int sd[256];
  int tid = threadIdx.x;
  int v = (tid < NBUCKET) ? tot[tid] : 0;
  sd[tid] = v;
  __syncthreads();
  for (int off = 1; off < 256; off <<= 1) {
    int t = (tid >= off) ? sd[tid - off] : 0;
    __syncthreads();
    sd[tid] += t;
    __syncthreads();
  }
  if (tid < NBUCKET) base[tid] = sd[tid] - v;
}

__global__ __launch_bounds__(256) void edge_place(const int* __restrict__ src,
                                                  const int* __restrict__ dst,
                                                  const int* __restrict__ cnt,
                                                  const int* __restrict__ base,
                                                  int* __restrict__ bktbuf) {
  __shared__ int curs[NBUCKET];
  int tid = threadIdx.x, blk = blockIdx.x;
  if (tid < NBUCKET) curs[tid] = base[tid] + cnt[blk * NBUCKET + tid];
  __syncthreads();
  int beg = blk * EPB, end = beg + EPB > N_EDGES ? N_EDGES : beg + EPB;
  for (int i = beg + tid; i < end; i += 256) {
    int d = dst[i];
    int b = d >> BKT_BITS;
    int pos = atomicAdd(&curs[b], 1);
    bktbuf[pos] = src[i] | ((d & (BKT_SIZE - 1)) << 17);
  }
}

__global__ __launch_bounds__(256) void bucket_sort(const int* __restrict__ tot,
                                                   const int* __restrict__ bktbase,
                                                   const int* __restrict__ bktbuf,
                                                   int* __restrict__ rp,
                                                   int* __restrict__ ci) {
  __shared__ int hist[BKT_SIZE];
  __shared__ int partial[256];
  int b = blockIdx.x;
  int tid = threadIdx.x;
  int nb = tot[b];
  int base = bktbase[b];
  const int* buf = bktbuf + base;
  hist[tid] = 0;
  hist[tid + 256] = 0;
  __syncthreads();
  for (int i = tid; i < nb; i += 256) atomicAdd(&hist[buf[i] >> 17], 1);
  __syncthreads();
  int v0 = hist[2 * tid], v1 = hist[2 * tid + 1];
  int s = v0 + v1;
  partial[tid] = s;
  __syncthreads();
  for (int off = 1; off < 256; off <<= 1) {
    int t = (tid >= off) ? partial[tid - off] : 0;
    __syncthreads();
    partial[tid] += t;
    __syncthreads();
  }
  int excl = partial[tid] - s;
  int node0 = b * BKT_SIZE + 2 * tid;
  if (node0 < N_NODES) rp[node0] = base + excl;
  if (node0 + 1 < N_NODES) rp[node0 + 1] = base + excl + v0;
  __syncthreads();
  hist[2 * tid] = excl;
  hist[2 * tid + 1] = excl + v0;
  __syncthreads();
  for (int i = tid; i < nb; i += 256) {
    int p = buf[i];
    int pos = atomicAdd(&hist[p >> 17], 1);
    ci[base + pos] = p & 0x1FFFF;
  }
  if (b == 0 && tid == 0) rp[N_NODES] = N_EDGES;
}

// ---------------- aggregation ----------------
__global__ __launch_bounds__(256) void agg_kernel(const float* __restrict__ hin,
                                                  const int* __restrict__ rp,
                                                  const int* __restrict__ ci,
                                                  float* __restrict__ out) {
  int wid = (blockIdx.x * blockDim.x + threadIdx.x) >> 6;
  int lane = threadIdx.x & 63;
  if (wid >= N_NODES) return;
  int beg = rp[wid];
  int end = rp[wid + 1];
  float a0 = hin[wid * 64 + lane];
  float a1 = 0.f, a2 = 0.f, a3 = 0.f;
  int e = beg;
  for (; e + 4 <= end; e += 4) {
    int s0 = ci[e + 0];
    int s1 = ci[e + 1];
    int s2 = ci[e + 2];
    int s3 = ci[e + 3];
    a0 += hin[s0 * 64 + lane];
    a1 += hin[s1 * 64 + lane];
    a2 += hin[s2 * 64 + lane];
    a3 += hin[s3 * 64 + lane];
  }
  for (; e < end; ++e) a1 += hin[ci[e] * 64 + lane];
  out[wid * 64 + lane] = (a0 + a1) + (a2 + a3);
}

// ---------------- x @ W0a (128 -> 64) ----------------
__global__ __launch_bounds__(128) void proj_kernel(const float* __restrict__ x,
                                                   const float* __restrict__ W0a,
                                                   float* __restrict__ out) {
  __shared__ float lds[128 * 65];
  int tid = threadIdx.x;
  int nbase = blockIdx.x * 128;
  float acc[64];
#pragma unroll
  for (int d = 0; d < 64; ++d) acc[d] = 0.f;
#pragma unroll
  for (int ph = 0; ph < 2; ++ph) {
    __syncthreads();
    for (int j = tid; j < 128 * 64; j += 128) {
      int node = j >> 6, col = j & 63;
      float v = (nbase + node < N_NODES) ? x[(nbase + node) * 128 + ph * 64 + col] : 0.f;
      lds[node * 65 + col] = v;
    }
    __syncthreads();
#pragma unroll 4
    for (int k = 0; k < 64; ++k) {
      float zk = lds[tid * 65 + k];
      const float* wr = W0a + (ph * 64 + k) * 64;
#pragma unroll
      for (int d = 0; d < 64; ++d) acc[d] = fmaf(zk, wr[d], acc[d]);
    }
  }
  __syncthreads();
#pragma unroll
  for (int d = 0; d < 64; ++d) lds[tid * 65 + d] = acc[d];
  __syncthreads();
  for (int j = tid; j < 128 * 64; j += 128) {
    int node = nbase + (j >> 6);
    if (node < N_NODES) out[node * 64 + (j & 63)] = lds[(j >> 6) * 65 + (j & 63)];
  }
}

// ---------------- conv0 tail ----------------
__global__ __launch_bounds__(128) void mlp0_kernel(const float* __restrict__ zin,
                                                   const float* __restrict__ ba,
                                                   const float* __restrict__ g,
                                                   const float* __restrict__ be,
                                                   const float* __restrict__ Wb,
                                                   const float* __restrict__ bb,
                                                   float* __restrict__ out) {
  __shared__ float lds[128 * 65];
  int tid = threadIdx.x;
  int nbase = blockIdx.x * 128;
  for (int j = tid; j < 128 * 64; j += 128) {
    int node = j >> 6, col = j & 63;
    float v = (nbase + node < N_NODES) ? zin[(nbase + node) * 64 + col] : 0.f;
    float t = fmaf((v + ba[col]) * BN_SCALE, g[col], be[col]);
    lds[node * 65 + col] = relu(t);
  }
  __syncthreads();
  float acc[64];
#pragma unroll
  for (int d = 0; d < 64; ++d) acc[d] = bb[d];
#pragma unroll 4
  for (int k = 0; k < 64; ++k) {
    float zk = lds[tid * 65 + k];
    const float* wr = Wb + k * 64;
#pragma unroll
    for (int d = 0; d < 64; ++d) acc[d] = fmaf(zk, wr[d], acc[d]);
  }
  __syncthreads();
#pragma unroll
  for (int d = 0; d < 64; ++d) lds[tid * 65 + d] = relu(acc[d]);
  __syncthreads();
  for (int j = tid; j < 128 * 64; j += 128) {
    int node = nbase + (j >> 6);
    if (node < N_NODES) out[node * 64 + (j & 63)] = lds[(j >> 6) * 65 + (j & 63)];
  }
}

// ---------------- convs 1,2 ----------------
__global__ __launch_bounds__(128) void mlp2_kernel(const float* __restrict__ zin,
                                                   const float* __restrict__ Wa,
                                                   const float* __restrict__ ba,
                                                   const float* __restrict__ g,
                                                   const float* __restrict__ be,
                                                   const float* __restrict__ Wb,
                                                   const float* __restrict__ bb,
                                                   float* __restrict__ out) {
  __shared__ float lds[128 * 65];
  int tid = threadIdx.x;
  int nbase = blockIdx.x * 128;
  for (int j = tid; j < 128 * 64; j += 128) {
    int node = j >> 6, col = j & 63;
    float v = (nbase + node < N_NODES) ? zin[(nbase + node) * 64 + col] : 0.f;
    lds[node * 65 + col] = v;
  }
  __syncthreads();
  float acc[64];
#pragma unroll
  for (int d = 0; d < 64; ++d) acc[d] = ba[d];
#pragma unroll 4
  for (int k = 0; k < 64; ++k) {
    float zk = lds[tid * 65 + k];
    const float* wr = Wa + k * 64;
#pragma unroll
    for (int d = 0; d < 64; ++d) acc[d] = fmaf(zk, wr[d], acc[d]);
  }
#pragma unroll
  for (int d = 0; d < 64; ++d) {
    float t = fmaf(acc[d] * BN_SCALE, g[d], be[d]);
    lds[tid * 65 + d] = relu(t);
  }
#pragma unroll
  for (int d = 0; d < 64; ++d) acc[d] = bb[d];
#pragma unroll 4
  for (int k = 0; k < 64; ++k) {
    float zk = lds[tid * 65 + k];
    const float* wr = Wb + k * 64;
#pragma unroll
    for (int d = 0; d < 64; ++d) acc[d] = fmaf(zk, wr[d], acc[d]);
  }
  __syncthreads();
#pragma unroll
  for (int d = 0; d < 64; ++d) lds[tid * 65 + d] = relu(acc[d]);
  __syncthreads();
  for (int j = tid; j < 128 * 64; j += 128) {
    int node = nbase + (j >> 6);
    if (node < N_NODES) out[node * 64 + (j & 63)] = lds[(j >> 6) * 65 + (j & 63)];
  }
}

// ---------------- pool ----------------
__global__ __launch_bounds__(256) void pool_kernel(const float* __restrict__ h,
                                                   const int* __restrict__ batch,
                                                   float* __restrict__ hp) {
  const int CH = (N_NODES + 1023) / 1024;
  int w = (blockIdx.x * blockDim.x + threadIdx.x) >> 6;
  int lane = threadIdx.x & 63;
  int start = w * CH;
  if (start >= N_NODES) return;
  int end = start + CH;
  if (end > N_NODES) end = N_NODES;
  int cur = batch[start];
  float acc = 0.f;
  for (int n = start; n < end; ++n) {
    int b = batch[n];
    if (b != cur) {
      atomicAdd(&hp[cur * 64 + lane], acc);
      acc = 0.f;
      cur = b;
    }
    acc += h[n * 64 + lane];
  }
  atomicAdd(&hp[cur * 64 + lane], acc);
}

// ---------------- classifier: 64 blocks (graph) x 64 threads (dim) ----------------
__global__ __launch_bounds__(64) void cls_kernel(const float* __restrict__ hp,
                                                 const float* __restrict__ Wl1,
                                                 const float* __restrict__ bl1,
                                                 const float* __restrict__ Wl2,
                                                 const float* __restrict__ bl2,
                                                 float* __restrict__ out) {
  int g = blockIdx.x;
  int d = threadIdx.x;
  const float* hrow = hp + g * 64;
  float acc = bl1[d];
#pragma unroll 8
  for (int k = 0; k < 64; ++k) {
    float v = hrow[k];
    float w = Wl1[k * 64 + d] + Wl1[(64 + k) * 64 + d] + Wl1[(128 + k) * 64 + d];
    acc = fmaf(v, w, acc);
  }
  float t = relu(acc);
  float p0 = t * Wl2[d * 2 + 0];
  float p1 = t * Wl2[d * 2 + 1];
#pragma unroll
  for (int off = 32; off > 0; off >>= 1) {
    p0 += __shfl_xor(p0, off, 64);
    p1 += __shfl_xor(p1, off, 64);
  }
  if (d == 0) {
    float z0 = p0 + bl2[0];
    float z1 = p1 + bl2[1];
    float m = fmaxf(z0, z1);
    float lse = m + logf(expf(z0 - m) + expf(z1 - m));
    out[g * 2 + 0] = z0 - lse;
    out[g * 2 + 1] = z1 - lse;
  }
}

extern "C" void kernel_launch(void* const* d_in, const int* in_sizes, int n_in,
                              void* d_out, int out_size, void* d_ws, size_t ws_size,
                              hipStream_t stream) {
  const float* x   = (const float*)d_in[0];
  const int*   ei  = (const int*)d_in[1];
  const int*   bat = (const int*)d_in[2];
  const float* W0a = (const float*)d_in[3];
  const float* b0a = (const float*)d_in[4];
  const float* g0  = (const float*)d_in[5];
  const float* be0 = (const float*)d_in[6];
  const float* W0b = (const float*)d_in[7];
  const float* b0b = (const float*)d_in[8];
  const float* Wsa = (const float*)d_in[9];
  const float* bsa = (const float*)d_in[10];
  const float* gs  = (const float*)d_in[11];
  const float* bes = (const float*)d_in[12];
  const float* Wsb = (const float*)d_in[13];
  const float* bsb = (const float*)d_in[14];
  const float* Wl1 = (const float*)d_in[15];
  const float* bl1 = (const float*)d_in[16];
  const float* Wl2 = (const float*)d_in[17];
  const float* bl2 = (const float*)d_in[18];
  const int* src = ei;
  const int* dst = ei + N_EDGES;

  char* ws = (char*)d_ws;
  size_t off = 0;
  auto alloc = [&](size_t bytes) { void* p = ws + off; off += (bytes + 255) & ~255ull; return p; };
  int* rp      = (int*)alloc((size_t)(N_NODES + 1) * 4);
  int* cnt     = (int*)alloc((size_t)NBLK * NBUCKET * 4);
  int* tot     = (int*)alloc((size_t)NBUCKET * 4);
  int* bktbase = (int*)alloc((size_t)NBUCKET * 4);
  int* ci      = (int*)alloc((size_t)N_EDGES * 4);
  float* bufA  = (float*)alloc((size_t)N_NODES * 64 * 4);
  float* bufZ  = (float*)alloc((size_t)N_NODES * 64 * 4);
  float* hp    = (float*)alloc((size_t)N_GRAPHS * 64 * 4);
  int* bktbuf  = (int*)bufZ;  // alias: consumed before bufZ first written

  hipMemsetAsync(hp, 0, (size_t)N_GRAPHS * 64 * 4, stream);

  edge_count<<<NBLK, 256, 0, stream>>>(dst, cnt);
  col_scan<<<NBUCKET, NBLK, 0, stream>>>(cnt, tot);
  base_scan<<<1, 256, 0, stream>>>(tot, bktbase);
  edge_place<<<NBLK, 256, 0, stream>>>(src, dst, cnt, bktbase, bktbuf);
  bucket_sort<<<NBUCKET, 256, 0, stream>>>(tot, bktbase, bktbuf, rp, ci);

  const int MB = (N_NODES + 127) / 128;    // 782
  const int AB = (N_NODES + 3) / 4;        // 25000 blocks of 4 waves

  proj_kernel<<<MB, 128, 0, stream>>>(x, W0a, bufA);
  agg_kernel<<<AB, 256, 0, stream>>>(bufA, rp, ci, bufZ);
  mlp0_kernel<<<MB, 128, 0, stream>>>(bufZ, b0a, g0, be0, W0b, b0b, bufA);

  for (int l = 0; l < 2; ++l) {
    agg_kernel<<<AB, 256, 0, stream>>>(bufA, rp, ci, bufZ);
    mlp2_kernel<<<MB, 128, 0, stream>>>(bufZ, Wsa + l * 4096, bsa + l * 64, gs + l * 64,
                                        bes + l * 64, Wsb + l * 4096, bsb + l * 64, bufA);
  }

  pool_kernel<<<256, 256, 0, stream>>>(bufA, bat, hp);
  cls_kernel<<<N_GRAPHS, 64, 0, stream>>>(hp, Wl1, bl1, Wl2, bl2, (float*)d_out);
}